// Round 13
// baseline (1854.752 us; speedup 1.0000x reference)
//
#include <hip/hip_runtime.h>
#include <math.h>

// B=256, T=2048, H=150. Sequential GRU, relu'd hidden, scalar linear head.
// 1 block / batch element (256 blocks = 256 CUs), 512 threads.
//
// R13 = R12's chain-split phase 1 (wave quarter q computes stride-4 chain
// a_q for rows 4idx..4idx+3; weights explicit v[100:251]; op_sel pk_fma)
// restructured to ONE barrier per step:
//   * Gate phase runs IN-WAVE: lane m of wave q computes the full gate
//     update for row j=4m+q (redundant across the 2 waves of a quarter,
//     deterministic => bit-identical). h_t therefore lands in exactly the
//     lane the next step's v_readlane reads -- the h LDS round trip and
//     barrier2 are GONE.
//   * Partials in transposed layout T[chain][row&3][row>>2]: phase-1
//     writes (4x b32, lane-consecutive) and gate reads (12x b32,
//     lane-consecutive) are ALL bank-conflict-free (R12: 6.1e7 conflicts).
//   * T is double-buffered (t&1) so the single barrier covers both RAW
//     (partials) and WAR (next step's writes) hazards.
// Gate tree verbatim R12: pre = ((c0+c1)+(c2+c3))+bhh; y = row-450 chain
// dots combined by tid 38 (wave 0 lane 38), written to LDS yout.

#define BB 256
#define TT 2048
#define HH 150
#define H3 450

typedef float fx2 __attribute__((ext_vector_type(2)));

// Clobber list for explicit weight registers v100..v251.
#define WCLOB \
  "v100","v101","v102","v103","v104","v105","v106","v107","v108","v109", \
  "v110","v111","v112","v113","v114","v115","v116","v117","v118","v119", \
  "v120","v121","v122","v123","v124","v125","v126","v127","v128","v129", \
  "v130","v131","v132","v133","v134","v135","v136","v137","v138","v139", \
  "v140","v141","v142","v143","v144","v145","v146","v147","v148","v149", \
  "v150","v151","v152","v153","v154","v155","v156","v157","v158","v159", \
  "v160","v161","v162","v163","v164","v165","v166","v167","v168","v169", \
  "v170","v171","v172","v173","v174","v175","v176","v177","v178","v179", \
  "v180","v181","v182","v183","v184","v185","v186","v187","v188","v189", \
  "v190","v191","v192","v193","v194","v195","v196","v197","v198","v199", \
  "v200","v201","v202","v203","v204","v205","v206","v207","v208","v209", \
  "v210","v211","v212","v213","v214","v215","v216","v217","v218","v219", \
  "v220","v221","v222","v223","v224","v225","v226","v227","v228","v229", \
  "v230","v231","v232","v233","v234","v235","v236","v237","v238","v239", \
  "v240","v241","v242","v243","v244","v245","v246","v247","v248","v249", \
  "v250","v251"

// Load one k-slot (offset OFF = 16*m bytes) for all 4 rows.
#define LD4(vA0,vA1,vB0,vB1,OFF) \
  "global_load_dword v" #vA0 ", %[b0], off offset:" #OFF "\n\t" \
  "global_load_dword v" #vA1 ", %[b1], off offset:" #OFF "\n\t" \
  "global_load_dword v" #vB0 ", %[b2], off offset:" #OFF "\n\t" \
  "global_load_dword v" #vB1 ", %[b3], off offset:" #OFF "\n\t"

// pk_fma with src0-low broadcast to both packed lanes.
#define PKB(sp, vp, acc) \
  "v_pk_fma_f32 " acc ", " sp ", " vp ", " acc " op_sel:[0,0,0] op_sel_hi:[0,1,1]\n\t"

// 4 k-elems: 4 readlanes (even SGPRs only) then 8 broadcast-pk_fmas.
#define G4(m0,m1,m2,m3, A0,B0, A1,B1, A2,B2, A3,B3) \
  "v_readlane_b32 s20, %[hq], " #m0 "\n\t" \
  "v_readlane_b32 s22, %[hq], " #m1 "\n\t" \
  "v_readlane_b32 s24, %[hq], " #m2 "\n\t" \
  "v_readlane_b32 s26, %[hq], " #m3 "\n\t" \
  PKB("s[20:21]", A0, "%[a01]") PKB("s[20:21]", B0, "%[a23]") \
  PKB("s[22:23]", A1, "%[a01]") PKB("s[22:23]", B1, "%[a23]") \
  PKB("s[24:25]", A2, "%[a01]") PKB("s[24:25]", B2, "%[a23]") \
  PKB("s[26:27]", A3, "%[a01]") PKB("s[26:27]", B3, "%[a23]")

__global__ __launch_bounds__(512, 2) void gru_seq_kernel(
    const float* __restrict__ input,   // [B,T]
    const float* __restrict__ W_ih,    // [450,1]
    const float* __restrict__ W_hh,    // [450,150]
    const float* __restrict__ b_ih,    // [450]
    const float* __restrict__ b_hh,    // [450]
    const float* __restrict__ W_lin,   // [1,150]
    const float* __restrict__ b_lin,   // [1]
    float* __restrict__ out)           // [B,T]
{
    const int b    = blockIdx.x;
    const int tid  = threadIdx.x;
    const int lane = tid & 63;
    const int wid  = tid >> 6;               // 0..7
    const int q    = wid & 3;                // wave-uniform chain/quarter
    const int idx  = ((wid >> 2) << 6) + lane;   // 0..127

    __shared__ float xrow[TT];         // 8 KB input row
    __shared__ float Tbuf[2][2048];    // 16 KB partials, double-buffered:
                                       // T[c*512 + (row&3)*128 + (row>>2)]
    __shared__ float yout[TT];         // 8 KB y buffer

    // ---- prologue -------------------------------------------------------
    ((float4*)xrow)[tid] = ((const float4*)(input + (size_t)b * TT))[tid];

    // Phase-1 weights: rows 4idx..4idx+3, chain q. Row 450 = W_lin (y-row),
    // rows >= 451 clamp to 449 (junk, never read).
    const int r0 = 4 * idx;
#define ROWP(r) ((r) == H3 ? W_lin : W_hh + ((r) < H3 ? (r) : (H3 - 1)) * HH)
    const float* b0 = ROWP(r0)     + q;   // chain q: element k = 4m+q
    const float* b1 = ROWP(r0 + 1) + q;
    const float* b2 = ROWP(r0 + 2) + q;
    const float* b3 = ROWP(r0 + 3) + q;

    asm volatile(
        LD4(100,101,176,177,0)    LD4(102,103,178,179,16)
        LD4(104,105,180,181,32)   LD4(106,107,182,183,48)
        LD4(108,109,184,185,64)   LD4(110,111,186,187,80)
        LD4(112,113,188,189,96)   LD4(114,115,190,191,112)
        LD4(116,117,192,193,128)  LD4(118,119,194,195,144)
        LD4(120,121,196,197,160)  LD4(122,123,198,199,176)
        LD4(124,125,200,201,192)  LD4(126,127,202,203,208)
        LD4(128,129,204,205,224)  LD4(130,131,206,207,240)
        LD4(132,133,208,209,256)  LD4(134,135,210,211,272)
        LD4(136,137,212,213,288)  LD4(138,139,214,215,304)
        LD4(140,141,216,217,320)  LD4(142,143,218,219,336)
        LD4(144,145,220,221,352)  LD4(146,147,222,223,368)
        LD4(148,149,224,225,384)  LD4(150,151,226,227,400)
        LD4(152,153,228,229,416)  LD4(154,155,230,231,432)
        LD4(156,157,232,233,448)  LD4(158,159,234,235,464)
        LD4(160,161,236,237,480)  LD4(162,163,238,239,496)
        LD4(164,165,240,241,512)  LD4(166,167,242,243,528)
        LD4(168,169,244,245,544)  LD4(170,171,246,247,560)
        LD4(172,173,248,249,576)
        "s_waitcnt vmcnt(0)\n\t"
        :
        : [b0] "v"(b0), [b1] "v"(b1), [b2] "v"(b2), [b3] "v"(b3)
        : WCLOB, "memory");
    // m=37: k=148+q. Real for q<2; for q>=2 h[150..151]=0 (exact), load
    // in-bounds junk to avoid OOB.
    {
        const int t37 = (q < 2) ? 148 : 144;
        float w0 = b0[t37], w1 = b1[t37], w2 = b2[t37], w3 = b3[t37];
        asm volatile(
            "v_mov_b32 v174, %0\n\tv_mov_b32 v175, %1\n\t"
            "v_mov_b32 v250, %2\n\tv_mov_b32 v251, %3\n\t"
            :: "v"(w0), "v"(w1), "v"(w2), "v"(w3)
            : "v174","v175","v250","v251");
    }

    // Gate-lane constants: lane m of wave q owns row j = 4m+q.
    const int m   = (lane < 38) ? lane : 37;     // clamped for safe offsets
    const int j   = 4 * lane + q;                // true row id
    const int act = (j < HH);
    const int jc  = act ? j : (HH - 1);
    const float wih_r = W_ih[jc];          const float bih_r = b_ih[jc];
    const float bhh_r = b_hh[jc];
    const float wih_z = W_ih[HH + jc];     const float bih_z = b_ih[HH + jc];
    const float bhh_z = b_hh[HH + jc];
    const float wih_n = W_ih[2*HH + jc];   const float bih_n = b_ih[2*HH + jc];
    const float bhh_n = b_hh[2*HH + jc];
    const float blin  = b_lin[0];

    // Transposed read offsets (floats): addr(c,row) = c*512+(row&3)*128+(row>>2)
    const int o_r = q * 128 + m;                         // row j
    const int iz  = (q < 2) ? (q + 2) : (q - 2);         // row 150+j
    const int gz  = (q < 2) ? (m + 37) : (m + 38);
    const int o_z = iz * 128 + gz;
    const int o_n = q * 128 + m + 75;                    // row 300+j
    const int o_y = 2 * 128 + 112;                       // row 450

    float hq = 0.f;                    // lane m holds h[4m+q]; lanes>=38: 0
    float* outb = out + (size_t)b * TT;

    __syncthreads();

    // ---- recurrence: ONE barrier per step -------------------------------
    // Iteration t: phase 1 dots h_{t-1} (in-register); barrier; gate phase
    // computes h_t in-lane. Extra iteration t==TT yields y_{TT-1} only.
    for (int t = 0; t <= TT; ++t) {
        float* Tc = Tbuf[t & 1];

        // phase 1: chain a_q of rows r0..r3; h broadcast via readlane of hq.
        fx2 a01; a01.x = 0.f; a01.y = 0.f;
        fx2 a23; a23.x = 0.f; a23.y = 0.f;
        asm volatile(
            G4( 0, 1, 2, 3, "v[100:101]","v[176:177]", "v[102:103]","v[178:179]",
                            "v[104:105]","v[180:181]", "v[106:107]","v[182:183]")
            G4( 4, 5, 6, 7, "v[108:109]","v[184:185]", "v[110:111]","v[186:187]",
                            "v[112:113]","v[188:189]", "v[114:115]","v[190:191]")
            G4( 8, 9,10,11, "v[116:117]","v[192:193]", "v[118:119]","v[194:195]",
                            "v[120:121]","v[196:197]", "v[122:123]","v[198:199]")
            G4(12,13,14,15, "v[124:125]","v[200:201]", "v[126:127]","v[202:203]",
                            "v[128:129]","v[204:205]", "v[130:131]","v[206:207]")
            G4(16,17,18,19, "v[132:133]","v[208:209]", "v[134:135]","v[210:211]",
                            "v[136:137]","v[212:213]", "v[138:139]","v[214:215]")
            G4(20,21,22,23, "v[140:141]","v[216:217]", "v[142:143]","v[218:219]",
                            "v[144:145]","v[220:221]", "v[146:147]","v[222:223]")
            G4(24,25,26,27, "v[148:149]","v[224:225]", "v[150:151]","v[226:227]",
                            "v[152:153]","v[228:229]", "v[154:155]","v[230:231]")
            G4(28,29,30,31, "v[156:157]","v[232:233]", "v[158:159]","v[234:235]",
                            "v[160:161]","v[236:237]", "v[162:163]","v[238:239]")
            "v_readlane_b32 s20, %[hq], 32\n\t"
            "v_readlane_b32 s22, %[hq], 33\n\t"
            "v_readlane_b32 s24, %[hq], 34\n\t"
            "v_readlane_b32 s26, %[hq], 35\n\t"
            "v_readlane_b32 s28, %[hq], 36\n\t"
            "v_readlane_b32 s30, %[hq], 37\n\t"
            PKB("s[20:21]", "v[164:165]", "%[a01]")
            PKB("s[20:21]", "v[240:241]", "%[a23]")
            PKB("s[22:23]", "v[166:167]", "%[a01]")
            PKB("s[22:23]", "v[242:243]", "%[a23]")
            PKB("s[24:25]", "v[168:169]", "%[a01]")
            PKB("s[24:25]", "v[244:245]", "%[a23]")
            PKB("s[26:27]", "v[170:171]", "%[a01]")
            PKB("s[26:27]", "v[246:247]", "%[a23]")
            PKB("s[28:29]", "v[172:173]", "%[a01]")
            PKB("s[28:29]", "v[248:249]", "%[a23]")
            PKB("s[30:31]", "v[174:175]", "%[a01]")
            PKB("s[30:31]", "v[250:251]", "%[a23]")
            : [a01] "+v"(a01), [a23] "+v"(a23)
            : [hq] "v"(hq)
            : "s20","s22","s24","s26","s28","s30", WCLOB);

        // Conflict-free transposed partial stores (lane-consecutive b32 x4).
        float* Tw = Tc + (q << 9) + idx;
        Tw[0]   = a01.x;    // row 4idx
        Tw[128] = a01.y;    // row 4idx+1
        Tw[256] = a23.x;    // row 4idx+2
        Tw[384] = a23.y;    // row 4idx+3
        __syncthreads();

        // gate phase (in-wave, redundant per quarter): lane m -> row j=4m+q.
        // pre = ((c0+c1)+(c2+c3)) + bhh -- verbatim R12 tree.
        {
            int tx = (t < TT) ? t : (TT - 1);
            float x  = xrow[tx];
            float pr = ((Tc[o_r]        + Tc[o_r + 512])
                      + (Tc[o_r + 1024] + Tc[o_r + 1536])) + bhh_r;
            float pz = ((Tc[o_z]        + Tc[o_z + 512])
                      + (Tc[o_z + 1024] + Tc[o_z + 1536])) + bhh_z;
            float pn = ((Tc[o_n]        + Tc[o_n + 1536 - 1024])  // +512
                      + (Tc[o_n + 1024] + Tc[o_n + 1536])) + bhh_n;
            float gr = fmaf(x, wih_r, bih_r) + pr;
            float gz_ = fmaf(x, wih_z, bih_z) + pz;
            float r  = 1.f / (1.f + __expf(-gr));
            float z  = 1.f / (1.f + __expf(-gz_));
            float ta = fmaf(x, wih_n, bih_n) + r * pn;
            ta = fminf(fmaxf(ta, -15.f), 15.f);
            float e  = __expf(2.f * ta);
            float n  = (e - 1.f) / (e + 1.f);        // tanh
            float hnew = fmaf(z, hq - n, n);         // (1-z)*n + z*h
            hnew = fmaxf(hnew, 0.f);                 // relu
            hq = act ? hnew : 0.f;                   // pad lanes stay 0
        }
        // y_{t-1} from row-450 chain partials (tid 38 = wave 0 lane 38,
        // inactive in gate mask). Same tree as R12.
        if (tid == 38 && t > 0) {
            yout[t - 1] = ((Tc[o_y]        + Tc[o_y + 512])
                         + (Tc[o_y + 1024] + Tc[o_y + 1536])) + blin;
        }
    }

    __syncthreads();
    // ---- epilogue: coalesced y dump (the loop's only global write) -------
    ((float4*)outb)[tid] = ((const float4*)yout)[tid];
}

extern "C" void kernel_launch(void* const* d_in, const int* in_sizes, int n_in,
                              void* d_out, int out_size, void* d_ws, size_t ws_size,
                              hipStream_t stream) {
    const float* input = (const float*)d_in[0];
    const float* W_ih  = (const float*)d_in[1];
    const float* W_hh  = (const float*)d_in[2];
    const float* b_ih  = (const float*)d_in[3];
    const float* b_hh  = (const float*)d_in[4];
    const float* W_lin = (const float*)d_in[5];
    const float* b_lin = (const float*)d_in[6];
    float* out = (float*)d_out;

    gru_seq_kernel<<<dim3(BB), dim3(512), 0, stream>>>(
        input, W_ih, W_hh, b_ih, b_hh, W_lin, b_lin, out);
}